// Round 11
// baseline (771.675 us; speedup 1.0000x reference)
//
#include <hip/hip_runtime.h>

#define N_NODES  100000
#define N_EDGES  1600000
#define HIDDEN   128
#define STEPS    4
#define N_GRAPHS 64
#define NBUCK    256
#define BWID     391   // nodes per bucket: 256*391 = 100096 >= 100000
#define BCAP     7168  // fixed ebuf slots per bucket (mean 6250, +11 sigma)
#define OUT_P    136   // output-staging row pitch (u16)

typedef unsigned short u16;
typedef unsigned int   u32;
typedef unsigned long long u64;
typedef __attribute__((ext_vector_type(8))) short bf16x8;
typedef __attribute__((ext_vector_type(4))) float f32x4;

__device__ inline u16 f2bf(float f) {
  u32 u = __float_as_uint(f);
  u = (u + 0x7FFFu + ((u >> 16) & 1u)) >> 16;  // RTNE
  return (u16)u;
}
__device__ inline float bf2f(u16 b) { return __uint_as_float(((u32)b) << 16); }

__device__ inline float fast_sig(float x) { return 1.f / (1.f + __expf(-x)); }
__device__ inline float fast_tanh(float x) {
  x = fminf(fmaxf(x, -15.f), 15.f);
  float e = __expf(2.f * x);
  return (e - 1.f) / (e + 1.f);
}

// ---------------- CSR build (bucketed multisplit, fixed-capacity buckets) ----------------
__global__ __launch_bounds__(1024) void k_part(const int* __restrict__ esrc,
                                               const int* __restrict__ edst,
                                               int* __restrict__ gcursor,
                                               u64* __restrict__ ebuf) {
  __shared__ int hist[NBUCK];
  __shared__ int base[NBUCK];
  int tid = threadIdx.x;
  if (tid < NBUCK) hist[tid] = 0;
  __syncthreads();
  int e0 = blockIdx.x * 4096;
  int sv[4], dv[4], bk[4], rk[4];
  #pragma unroll
  for (int i = 0; i < 4; ++i) {
    int e = e0 + i * 1024 + tid;
    if (e < N_EDGES) {
      sv[i] = esrc[e];
      dv[i] = edst[e];
      bk[i] = (int)((u32)dv[i] / (u32)BWID);
      rk[i] = atomicAdd(&hist[bk[i]], 1);
    } else bk[i] = -1;
  }
  __syncthreads();
  if (tid < NBUCK) base[tid] = atomicAdd(&gcursor[tid], hist[tid]);
  __syncthreads();
  #pragma unroll
  for (int i = 0; i < 4; ++i) {
    if (bk[i] >= 0) {
      int pos = bk[i] * BCAP + base[bk[i]] + rk[i];
      ebuf[pos] = ((u64)(u32)dv[i] << 32) | (u32)sv[i];
    }
  }
}

__global__ void k_bscan(const int* __restrict__ gcursor, int* __restrict__ ebase) {
  __shared__ int buf[NBUCK];
  int t = threadIdx.x;
  int v = gcursor[t];
  buf[t] = v;
  __syncthreads();
  for (int off = 1; off < NBUCK; off <<= 1) {
    int u = 0;
    if (t >= off) u = buf[t - off];
    __syncthreads();
    buf[t] += u;
    __syncthreads();
  }
  ebase[t] = buf[t] - v;
  if (t == NBUCK - 1) ebase[NBUCK] = buf[t];
}

__global__ __launch_bounds__(1024) void k_csr(const u64* __restrict__ ebuf,
                                              const int* __restrict__ ebase,
                                              int* __restrict__ offs,
                                              int* __restrict__ csr) {
  __shared__ int lcnt[512];
  __shared__ int lofs[512];
  int b = blockIdx.x, tid = threadIdx.x;
  int n0 = b * BWID;
  int n1 = min(n0 + BWID, N_NODES);
  int nn = n1 - n0;
  int e0 = ebase[b];
  int cnt = ebase[b + 1] - e0;
  const u64* ebase_p = ebuf + (size_t)b * BCAP;
  if (tid < 512) lcnt[tid] = 0;
  __syncthreads();
  for (int e = tid; e < cnt; e += 1024) {
    int dst = (int)(ebase_p[e] >> 32);
    atomicAdd(&lcnt[dst - n0], 1);
  }
  __syncthreads();
  if (tid < 512) lofs[tid] = lcnt[tid];
  __syncthreads();
  for (int off = 1; off < 512; off <<= 1) {
    int v = 0;
    if (tid < 512 && tid >= off) v = lofs[tid - off];
    __syncthreads();
    if (tid < 512 && tid >= off) lofs[tid] += v;
    __syncthreads();
  }
  int nodeoff = 0;
  if (tid < 512) nodeoff = e0 + lofs[tid] - lcnt[tid];  // exclusive
  if (tid < 512) lofs[tid] = nodeoff;                   // reuse as cursor
  if (tid < nn) offs[n0 + tid] = nodeoff;
  if (b == 0 && tid == 0) offs[N_NODES] = N_EDGES;
  __syncthreads();
  for (int e = tid; e < cnt; e += 1024) {
    u64 p = ebase_p[e];
    int src = (int)(p & 0xffffffffull);
    int dst = (int)(p >> 32);
    int pos = atomicAdd(&lofs[dst - n0], 1);
    csr[pos] = src;
  }
}

// ---------------- combined weight build ----------------
// Column-interleaved fragment order: per kc chunk (32 k), slot = wave*8 + u with
// u = gate*2 + hu; slot covers B column c = gate*128 + wave*32 + hu*16 + nl.
// Address: bsw[st][kc][slot][quad][nl][kl]  (quad=(k>>3)&3, kl=k&7).
__global__ void k_wb(const float* __restrict__ W, const float* __restrict__ w_ih,
                     const float* __restrict__ w_hh, u16* __restrict__ bsw) {
  __shared__ float wrow[128];
  int b = blockIdx.x, st = b >> 8, k = b & 255, t = threadIdx.x;
  if (k < 128) wrow[t] = W[(st * 128 + k) * 128 + t];
  __syncthreads();
  int kc = k >> 5, quad = (k >> 3) & 3, kl = k & 7;
  u16* base = bsw + (size_t)st * 131072 + kc * 16384;
  #pragma unroll
  for (int gq = 0; gq < 4; ++gq) {
    int c = gq * 128 + t;
    float v;
    if (k < 128) {
      if (c < 384) {
        const float* wr = w_ih + c * 128;
        float sacc = 0.f;
        for (int j = 0; j < 128; ++j) sacc += wrow[j] * wr[j];
        v = sacc;
      } else v = 0.f;
    } else {
      int kk = k - 128;
      if (c < 256)      v = w_hh[c * 128 + kk];
      else if (c < 384) v = 0.f;
      else              v = w_hh[(c - 128) * 128 + kk];
    }
    int gi = c >> 7, cw = c & 127;
    int wv = cw >> 5, hu = (cw >> 4) & 1, nl = c & 15;
    int slot = wv * 8 + gi * 2 + hu;
    base[(slot * 4 + quad) * 128 + nl * 8 + kl] = f2bf(v);
  }
}

// ---------------- x -> bf16 ----------------
__global__ void k_convert(const float* __restrict__ x, u16* __restrict__ h) {
  int i = (blockIdx.x * 256 + threadIdx.x) * 4;
  float4 v = *(const float4*)(x + i);
  u16 o[4] = {f2bf(v.x), f2bf(v.y), f2bf(v.z), f2bf(v.w)};
  *(uint2*)(h + i) = *(uint2*)o;
}

// ---------------- fused gather + dual-GEMM + GRU step ----------------
// One block = 32 nodes. Phase 1: stage h rows into Asw h-half (coalesced) and
// gather-sum neighbor rows directly into Asw s-half (R9 quarter-wave 4-deep
// pipeline; q==0 lane's reduced uint4 lands exactly in one fragment slot).
// Phase 2 (after ONE barrier): barrier-free B-direct MFMA K-loop + register
// GRU combine + coalesced store. Co-resident blocks overlap phase types.
__device__ inline void acc8(float* a, uint4 p) {
  a[0] += bf2f((u16)(p.x & 0xffffu)); a[1] += bf2f((u16)(p.x >> 16));
  a[2] += bf2f((u16)(p.y & 0xffffu)); a[3] += bf2f((u16)(p.y >> 16));
  a[4] += bf2f((u16)(p.z & 0xffffu)); a[5] += bf2f((u16)(p.z >> 16));
  a[6] += bf2f((u16)(p.w & 0xffffu)); a[7] += bf2f((u16)(p.w >> 16));
}

__global__ __launch_bounds__(256, 3) void k_mpnn_step(
    const u16* __restrict__ h_mat, const int* __restrict__ csr,
    const int* __restrict__ offs, const u16* __restrict__ bsw,
    const float* __restrict__ b_ih, const float* __restrict__ b_hh,
    u16* __restrict__ h_out) {
  __shared__ u16 Asw[8192];       // 16 KB: A=[s|h], 32 rows x 256 k, frag-ordered
  __shared__ u16 Osw[32 * OUT_P]; // 8.7 KB out-stage

  const int tid  = threadIdx.x;
  const int wave = tid >> 6;
  const int lane = tid & 63;
  const int nl   = lane & 15;
  const int quad = lane >> 4;
  const int row0 = blockIdx.x * 32;   // 3125 * 32 == 100000 exactly

  {  // stage h rows -> Asw h-half (slots g*8+4+kc2)
    int r = tid >> 3;                  // 0..31
    int g = r >> 4, snl = r & 15;
    const u16* row = h_mat + (size_t)(row0 + r) * 128;
    #pragma unroll
    for (int t2 = 0; t2 < 2; ++t2) {
      int cb = (tid & 7) * 2 + t2;     // 8-col block 0..15
      int kc2 = cb >> 2, squad = cb & 3;
      uint4 v = *(const uint4*)(row + cb * 8);
      *(uint4*)&Asw[(((g * 8 + 4 + kc2) * 4 + squad) * 16 + snl) * 8] = v;
    }
  }

  {  // gather phase: wave handles 8 nodes; quarter-wave 4-deep pipeline per node
    int q = quad, sub = nl;
    for (int i = 0; i < 8; ++i) {
      int nloc = wave * 8 + i;
      int node = row0 + nloc;
      int beg = offs[node], end = offs[node + 1];
      float a[8] = {0.f, 0.f, 0.f, 0.f, 0.f, 0.f, 0.f, 0.f};
      int j = beg + q;
      for (; j + 12 < end; j += 16) {
        int s0 = csr[j], s1 = csr[j + 4], s2 = csr[j + 8], s3 = csr[j + 12];
        uint4 p0 = *(const uint4*)(h_mat + (size_t)s0 * 128 + sub * 8);
        uint4 p1 = *(const uint4*)(h_mat + (size_t)s1 * 128 + sub * 8);
        uint4 p2 = *(const uint4*)(h_mat + (size_t)s2 * 128 + sub * 8);
        uint4 p3 = *(const uint4*)(h_mat + (size_t)s3 * 128 + sub * 8);
        acc8(a, p0); acc8(a, p1); acc8(a, p2); acc8(a, p3);
      }
      for (; j < end; j += 4) {
        uint4 p0 = *(const uint4*)(h_mat + (size_t)csr[j] * 128 + sub * 8);
        acc8(a, p0);
      }
      #pragma unroll
      for (int v = 0; v < 8; ++v) {
        a[v] += __shfl_xor(a[v], 16);
        a[v] += __shfl_xor(a[v], 32);
      }
      if (q == 0) {
        int g = nloc >> 4, snl = nloc & 15;
        int kc2 = sub >> 2, squad = sub & 3;
        uint4 o;
        o.x = (u32)f2bf(a[0]) | ((u32)f2bf(a[1]) << 16);
        o.y = (u32)f2bf(a[2]) | ((u32)f2bf(a[3]) << 16);
        o.z = (u32)f2bf(a[4]) | ((u32)f2bf(a[5]) << 16);
        o.w = (u32)f2bf(a[6]) | ((u32)f2bf(a[7]) << 16);
        *(uint4*)&Asw[(((g * 8 + kc2) * 4 + squad) * 16 + snl) * 8] = o;
      }
    }
  }
  __syncthreads();

  // wave-private B fragment base (u16 units); slot u at +u*512, kc at +kc*16384
  const u16* bp = bsw + wave * 8 * 512 + lane * 8;

  f32x4 acc[2][8];
  #pragma unroll
  for (int g = 0; g < 2; ++g)
    #pragma unroll
    for (int u = 0; u < 8; ++u) acc[g][u] = (f32x4){0.f, 0.f, 0.f, 0.f};

  // active slot sets: kc<4 -> {0,1,2,3,4,5} (r,z,i_n); kc>=4 -> {0,1,2,3,6,7} (r,z,h_n)
  bf16x8 bcur[6], bnext[6];
  #pragma unroll
  for (int i = 0; i < 6; ++i) bcur[i] = *(const bf16x8*)(bp + i * 512);

  #pragma unroll
  for (int kc = 0; kc < 8; ++kc) {
    if (kc < 7) {
      #pragma unroll
      for (int i = 0; i < 6; ++i) {
        int us = (kc + 1 < 4) ? i : (i < 4 ? i : i + 2);
        bnext[i] = *(const bf16x8*)(bp + (kc + 1) * 16384 + us * 512);
      }
    }
    bf16x8 a0 = *(const bf16x8*)&Asw[kc * 512 + lane * 8];
    bf16x8 a1 = *(const bf16x8*)&Asw[(8 + kc) * 512 + lane * 8];
    #pragma unroll
    for (int i = 0; i < 6; ++i) {
      int u = (kc < 4) ? i : (i < 4 ? i : i + 2);
      acc[0][u] = __builtin_amdgcn_mfma_f32_16x16x32_bf16(a0, bcur[i], acc[0][u], 0, 0, 0);
      acc[1][u] = __builtin_amdgcn_mfma_f32_16x16x32_bf16(a1, bcur[i], acc[1][u], 0, 0, 0);
    }
    #pragma unroll
    for (int i = 0; i < 6; ++i) bcur[i] = bnext[i];
  }

  // biases: u = gate*2+hu, within-gate col cw = wave*32 + hu*16 + nl
  float bias[8];
  #pragma unroll
  for (int u = 0; u < 8; ++u) {
    int gi = u >> 1, hu = u & 1;
    int cw = wave * 32 + hu * 16 + nl;
    bias[u] = (gi == 0) ? b_ih[cw] + b_hh[cw]
            : (gi == 1) ? b_ih[128 + cw] + b_hh[128 + cw]
            : (gi == 2) ? b_ih[256 + cw]
                        : b_hh[256 + cw];
  }

  // register-resident GRU combine; results -> Osw out-stage
  #pragma unroll
  for (int g = 0; g < 2; ++g) {
    #pragma unroll
    for (int hu = 0; hu < 2; ++hu) {
      int cw = wave * 32 + hu * 16 + nl;     // output column
      int hbase = ((g * 8 + 4 + wave) * 4 + ((hu * 2 + (nl >> 3)) & 3)) * 128 + (nl & 7);
      #pragma unroll
      for (int i = 0; i < 4; ++i) {
        int m = quad * 4 + i;                // row within 16-row group
        float rv = fast_sig(acc[g][0 + hu][i] + bias[0 + hu]);
        float zv = fast_sig(acc[g][2 + hu][i] + bias[2 + hu]);
        float iv = acc[g][4 + hu][i] + bias[4 + hu];
        float hn = acc[g][6 + hu][i] + bias[6 + hu];
        float hv = bf2f(Asw[hbase + m * 8]);
        float n  = fast_tanh(iv + rv * hn);
        float o  = (1.f - zv) * n + zv * hv;
        Osw[(g * 16 + m) * OUT_P + cw] = f2bf(o);
      }
    }
  }
  __syncthreads();

  {  // coalesced store: 32 rows x 128 cols
    int r32 = tid >> 3, c0 = (tid & 7) * 16;
    uint4 v0 = *(const uint4*)&Osw[r32 * OUT_P + c0];
    uint4 v1 = *(const uint4*)&Osw[r32 * OUT_P + c0 + 8];
    uint4* dstp = (uint4*)(h_out + (size_t)(row0 + r32) * 128 + c0);
    dstp[0] = v0;
    dstp[1] = v1;
  }
}

// ---------------- relu + segment mean pool (two-phase, parallel) ----------------
__global__ void k_pool_partial(const u16* __restrict__ h, const int* __restrict__ batch,
                               float* __restrict__ acc) {
  int t = threadIdx.x;  // column 0..127
  int node0 = blockIdx.x * 125;
  int node1 = node0 + 125;
  int cur = batch[node0];
  float sum = 0.f;
  for (int r = node0; r < node1; ++r) {
    int g = batch[r];
    if (g != cur) {
      atomicAdd(&acc[cur * 128 + t], sum);
      sum = 0.f;
      cur = g;
    }
    sum += fmaxf(bf2f(h[(size_t)r * 128 + t]), 0.f);
  }
  atomicAdd(&acc[cur * 128 + t], sum);
}

__global__ void k_pool_div(const float* __restrict__ acc, const int* __restrict__ batch,
                           float* __restrict__ out) {
  __shared__ int se[2];
  int g = blockIdx.x, t = threadIdx.x;
  if (t < 2) {
    int target = g + t;
    int lo = 0, hi = N_NODES;
    while (lo < hi) { int mid = (lo + hi) >> 1; if (batch[mid] < target) lo = mid + 1; else hi = mid; }
    se[t] = lo;
  }
  __syncthreads();
  int cnt = se[1] - se[0];
  out[g * 128 + t] = acc[g * 128 + t] / (float)(cnt > 0 ? cnt : 1);
}

extern "C" void kernel_launch(void* const* d_in, const int* in_sizes, int n_in,
                              void* d_out, int out_size, void* d_ws, size_t ws_size,
                              hipStream_t stream) {
  const float* x     = (const float*)d_in[0];
  const int*   edges = (const int*)d_in[1];
  const int*   batch = (const int*)d_in[2];
  const float* W     = (const float*)d_in[3];
  const float* w_ih  = (const float*)d_in[4];
  const float* w_hh  = (const float*)d_in[5];
  const float* b_ih  = (const float*)d_in[6];
  const float* b_hh  = (const float*)d_in[7];
  float* out = (float*)d_out;

  char* w = (char*)d_ws;
  u16* buf0    = (u16*)(w);                 // 25,600,000 B  (h ping)
  u16* buf1    = (u16*)(w + 25600000);      // 25,600,000 B  (h pong)
  u16* bsw     = (u16*)(w + 51200000);      // 1,048,576 B
  float* acc   = (float*)(w + 52300032);    // 32,768 B  (pool accumulator)
  int* offs    = (int*)(w + 52710400);      // 400,004 B
  int* gcursor = (int*)(w + 53120768);      // 1,024 B
  int* ebase   = (int*)(w + 53123328);      // 1,028 B
  int* csr     = (int*)(w + 53531136);      // 6,400,000 B  -> total ~60 MB
  u64* ebuf    = (u64*)buf1;                // 14.7 MB; buf1 dead until step 1 writes it

  const int* esrc = edges;
  const int* edst = edges + N_EDGES;

  hipMemsetAsync(gcursor, 0, NBUCK * sizeof(int), stream);
  k_part<<<391, 1024, 0, stream>>>(esrc, edst, gcursor, ebuf);
  k_bscan<<<1, NBUCK, 0, stream>>>(gcursor, ebase);
  k_csr<<<NBUCK, 1024, 0, stream>>>(ebuf, ebase, offs, csr);
  k_wb<<<1024, 128, 0, stream>>>(W, w_ih, w_hh, bsw);
  k_convert<<<(N_NODES * HIDDEN) / 1024, 256, 0, stream>>>(x, buf0);
  hipMemsetAsync(acc, 0, N_GRAPHS * HIDDEN * sizeof(float), stream);

  u16* hcur = buf0;
  u16* hnxt = buf1;
  for (int st = 0; st < STEPS; ++st) {
    // reads hcur (gather srcs + GRU h), writes hnxt -- distinct buffers, no hazard
    k_mpnn_step<<<N_NODES / 32, 256, 0, stream>>>(hcur, csr, offs,
                                                  bsw + st * 131072,
                                                  b_ih, b_hh, hnxt);
    u16* tmp = hcur; hcur = hnxt; hnxt = tmp;
  }
  k_pool_partial<<<800, 128, 0, stream>>>(hcur, batch, acc);
  k_pool_div<<<N_GRAPHS, 128, 0, stream>>>(acc, batch, out);
}

// Round 12
// 598.046 us; speedup vs baseline: 1.2903x; 1.2903x over previous
//
#include <hip/hip_runtime.h>

#define N_NODES  100000
#define N_EDGES  1600000
#define HIDDEN   128
#define STEPS    4
#define N_GRAPHS 64
#define NBUCK    256
#define BWID     391   // nodes per bucket: 256*391 = 100096 >= 100000
#define BCAP     7168  // fixed ebuf slots per bucket (mean 6250, +11 sigma)

typedef unsigned short u16;
typedef unsigned int   u32;
typedef unsigned long long u64;
typedef __attribute__((ext_vector_type(8))) short bf16x8;
typedef __attribute__((ext_vector_type(4))) float f32x4;

__device__ inline u16 f2bf(float f) {
  u32 u = __float_as_uint(f);
  u = (u + 0x7FFFu + ((u >> 16) & 1u)) >> 16;  // RTNE
  return (u16)u;
}
__device__ inline float bf2f(u16 b) { return __uint_as_float(((u32)b) << 16); }

// rcp-based activations: no IEEE division sequence (div_scale/div_fixup),
// no clamps. tanh form 1-2/(1+e^{2x}) is NaN-free at +-inf.
__device__ inline float rcp_f(float x) { return __builtin_amdgcn_rcpf(x); }
__device__ inline float sig_f(float x) { return rcp_f(1.f + __expf(-x)); }
__device__ inline float tanh_f(float x) { return 1.f - 2.f * rcp_f(1.f + __expf(2.f * x)); }

// ---------------- CSR build (bucketed multisplit, fixed-capacity buckets) ----------------
__global__ __launch_bounds__(1024) void k_part(const int* __restrict__ esrc,
                                               const int* __restrict__ edst,
                                               int* __restrict__ gcursor,
                                               u64* __restrict__ ebuf) {
  __shared__ int hist[NBUCK];
  __shared__ int base[NBUCK];
  int tid = threadIdx.x;
  if (tid < NBUCK) hist[tid] = 0;
  __syncthreads();
  int e0 = blockIdx.x * 4096;
  int sv[4], dv[4], bk[4], rk[4];
  #pragma unroll
  for (int i = 0; i < 4; ++i) {
    int e = e0 + i * 1024 + tid;
    if (e < N_EDGES) {
      sv[i] = esrc[e];
      dv[i] = edst[e];
      bk[i] = (int)((u32)dv[i] / (u32)BWID);
      rk[i] = atomicAdd(&hist[bk[i]], 1);
    } else bk[i] = -1;
  }
  __syncthreads();
  if (tid < NBUCK) base[tid] = atomicAdd(&gcursor[tid], hist[tid]);
  __syncthreads();
  #pragma unroll
  for (int i = 0; i < 4; ++i) {
    if (bk[i] >= 0) {
      int pos = bk[i] * BCAP + base[bk[i]] + rk[i];
      ebuf[pos] = ((u64)(u32)dv[i] << 32) | (u32)sv[i];
    }
  }
}

__global__ void k_bscan(const int* __restrict__ gcursor, int* __restrict__ ebase) {
  __shared__ int buf[NBUCK];
  int t = threadIdx.x;
  int v = gcursor[t];
  buf[t] = v;
  __syncthreads();
  for (int off = 1; off < NBUCK; off <<= 1) {
    int u = 0;
    if (t >= off) u = buf[t - off];
    __syncthreads();
    buf[t] += u;
    __syncthreads();
  }
  ebase[t] = buf[t] - v;
  if (t == NBUCK - 1) ebase[NBUCK] = buf[t];
}

__global__ __launch_bounds__(1024) void k_csr(const u64* __restrict__ ebuf,
                                              const int* __restrict__ ebase,
                                              int* __restrict__ offs,
                                              int* __restrict__ csr) {
  __shared__ int lcnt[512];
  __shared__ int lofs[512];
  int b = blockIdx.x, tid = threadIdx.x;
  int n0 = b * BWID;
  int n1 = min(n0 + BWID, N_NODES);
  int nn = n1 - n0;
  int e0 = ebase[b];
  int cnt = ebase[b + 1] - e0;
  const u64* ebase_p = ebuf + (size_t)b * BCAP;
  if (tid < 512) lcnt[tid] = 0;
  __syncthreads();
  for (int e = tid; e < cnt; e += 1024) {
    int dst = (int)(ebase_p[e] >> 32);
    atomicAdd(&lcnt[dst - n0], 1);
  }
  __syncthreads();
  if (tid < 512) lofs[tid] = lcnt[tid];
  __syncthreads();
  for (int off = 1; off < 512; off <<= 1) {
    int v = 0;
    if (tid < 512 && tid >= off) v = lofs[tid - off];
    __syncthreads();
    if (tid < 512 && tid >= off) lofs[tid] += v;
    __syncthreads();
  }
  int nodeoff = 0;
  if (tid < 512) nodeoff = e0 + lofs[tid] - lcnt[tid];  // exclusive
  if (tid < 512) lofs[tid] = nodeoff;                   // reuse as cursor
  if (tid < nn) offs[n0 + tid] = nodeoff;
  if (b == 0 && tid == 0) offs[N_NODES] = N_EDGES;
  __syncthreads();
  for (int e = tid; e < cnt; e += 1024) {
    u64 p = ebase_p[e];
    int src = (int)(p & 0xffffffffull);
    int dst = (int)(p >> 32);
    int pos = atomicAdd(&lofs[dst - n0], 1);
    csr[pos] = src;
  }
}

// ---------------- combined weight build ----------------
// Column-interleaved fragment order: per kc chunk (32 k), slot = wave*8 + u with
// u = gate*2 + hu; slot covers B column c = gate*128 + wave*32 + hu*16 + nl.
// Address: bsw[st][kc][slot][quad][nl][kl]  (quad=(k>>3)&3, kl=k&7).
__global__ void k_wb(const float* __restrict__ W, const float* __restrict__ w_ih,
                     const float* __restrict__ w_hh, u16* __restrict__ bsw) {
  __shared__ float wrow[128];
  int b = blockIdx.x, st = b >> 8, k = b & 255, t = threadIdx.x;
  if (k < 128) wrow[t] = W[(st * 128 + k) * 128 + t];
  __syncthreads();
  int kc = k >> 5, quad = (k >> 3) & 3, kl = k & 7;
  u16* base = bsw + (size_t)st * 131072 + kc * 16384;
  #pragma unroll
  for (int gq = 0; gq < 4; ++gq) {
    int c = gq * 128 + t;
    float v;
    if (k < 128) {
      if (c < 384) {
        const float* wr = w_ih + c * 128;
        float sacc = 0.f;
        for (int j = 0; j < 128; ++j) sacc += wrow[j] * wr[j];
        v = sacc;
      } else v = 0.f;
    } else {
      int kk = k - 128;
      if (c < 256)      v = w_hh[c * 128 + kk];
      else if (c < 384) v = 0.f;
      else              v = w_hh[(c - 128) * 128 + kk];
    }
    int gi = c >> 7, cw = c & 127;
    int wv = cw >> 5, hu = (cw >> 4) & 1, nl = c & 15;
    int slot = wv * 8 + gi * 2 + hu;
    base[(slot * 4 + quad) * 128 + nl * 8 + kl] = f2bf(v);
  }
}

// ---------------- x -> bf16 ----------------
__global__ void k_convert(const float* __restrict__ x, u16* __restrict__ h) {
  int i = (blockIdx.x * 256 + threadIdx.x) * 4;
  float4 v = *(const float4*)(x + i);
  u16 o[4] = {f2bf(v.x), f2bf(v.y), f2bf(v.z), f2bf(v.w)};
  *(uint2*)(h + i) = *(uint2*)o;
}

// ---------------- neighbor gather-sum: s[dst] = sum h[src] ----------------
// One node per wave; quarter-wave q takes edges j = beg+q+4t. 4-deep software
// pipeline: 4 csr reads + 4 independent 16B row loads in flight before any
// accumulation -> hides L2/LLC latency.  (R9-proven form, unchanged.)
__device__ inline void acc8(float* a, uint4 p) {
  a[0] += bf2f((u16)(p.x & 0xffffu)); a[1] += bf2f((u16)(p.x >> 16));
  a[2] += bf2f((u16)(p.y & 0xffffu)); a[3] += bf2f((u16)(p.y >> 16));
  a[4] += bf2f((u16)(p.z & 0xffffu)); a[5] += bf2f((u16)(p.z >> 16));
  a[6] += bf2f((u16)(p.w & 0xffffu)); a[7] += bf2f((u16)(p.w >> 16));
}

__global__ void k_gather(const u16* __restrict__ h, const int* __restrict__ csr,
                         const int* __restrict__ offs, u16* __restrict__ s) {
  int node = blockIdx.x * 4 + (threadIdx.x >> 6);
  int lane = threadIdx.x & 63;
  int q   = lane >> 4;
  int sub = lane & 15;
  int beg = offs[node], end = offs[node + 1];
  float a[8] = {0.f, 0.f, 0.f, 0.f, 0.f, 0.f, 0.f, 0.f};
  int j = beg + q;
  for (; j + 12 < end; j += 16) {
    int s0 = csr[j], s1 = csr[j + 4], s2 = csr[j + 8], s3 = csr[j + 12];
    uint4 p0 = *(const uint4*)(h + (size_t)s0 * 128 + sub * 8);
    uint4 p1 = *(const uint4*)(h + (size_t)s1 * 128 + sub * 8);
    uint4 p2 = *(const uint4*)(h + (size_t)s2 * 128 + sub * 8);
    uint4 p3 = *(const uint4*)(h + (size_t)s3 * 128 + sub * 8);
    acc8(a, p0); acc8(a, p1); acc8(a, p2); acc8(a, p3);
  }
  for (; j < end; j += 4) {
    int s0 = csr[j];
    uint4 p0 = *(const uint4*)(h + (size_t)s0 * 128 + sub * 8);
    acc8(a, p0);
  }
  #pragma unroll
  for (int i = 0; i < 8; ++i) {
    a[i] += __shfl_xor(a[i], 16);
    a[i] += __shfl_xor(a[i], 32);
  }
  if (q == 0) {
    uint4 o;
    o.x = (u32)f2bf(a[0]) | ((u32)f2bf(a[1]) << 16);
    o.y = (u32)f2bf(a[2]) | ((u32)f2bf(a[3]) << 16);
    o.z = (u32)f2bf(a[4]) | ((u32)f2bf(a[5]) << 16);
    o.w = (u32)f2bf(a[6]) | ((u32)f2bf(a[7]) << 16);
    *(uint4*)(s + (size_t)node * 128 + sub * 8) = o;
  }
}

// ---------------- fused dual-GEMM + GRU cell ----------------
// 32 rows/block, 4 waves, wave w owns output cols w*32..+31 (all 4 gates).
// B direct global->VGPR (L2-resident, frag-ordered) with one-kc-ahead double
// buffering -> no K-loop barriers. Epilogue: rcp-based activations (no IEEE
// div sequences, no clamps) + DIRECT u16 global stores (no LDS out-stage, no
// final barrier). In-place safe: block writes only its own 32 rows, after
// staging them to LDS.
__global__ __launch_bounds__(256, 3) void k_gemm_gru(
    const u16* __restrict__ s_mat, const u16* __restrict__ h_mat,
    const u16* __restrict__ bsw, const float* __restrict__ b_ih,
    const float* __restrict__ b_hh, u16* __restrict__ h_out) {
  __shared__ u16 Asw[8192];       // 16 KB: A=[s|h], 32 rows x 256 k, frag-ordered

  const int tid  = threadIdx.x;
  const int wave = tid >> 6;
  const int lane = tid & 63;
  const int nl   = lane & 15;
  const int quad = lane >> 4;
  const int row0 = blockIdx.x * 32;   // 3125 * 32 == 100000 exactly

  {  // stage A: thread (half, squad, snl) loads 4x16B; contiguous LDS writes per wave
    int snl = tid & 15, squad = (tid >> 4) & 3, sel = tid >> 6;
    int g = sel & 1, half = sel >> 1;             // g: 16-row group; half: 0=s, 1=h
    const u16* row = (half ? h_mat : s_mat) + (size_t)(row0 + g * 16 + snl) * 128;
    #pragma unroll
    for (int kc2 = 0; kc2 < 4; ++kc2) {
      uint4 v = *(const uint4*)(row + kc2 * 32 + squad * 8);
      *(uint4*)&Asw[(((g * 8 + half * 4 + kc2) * 4 + squad) * 16 + snl) * 8] = v;
    }
  }
  __syncthreads();

  // wave-private B fragment base (u16 units); slot u at +u*512, kc at +kc*16384
  const u16* bp = bsw + wave * 8 * 512 + lane * 8;

  f32x4 acc[2][8];
  #pragma unroll
  for (int g = 0; g < 2; ++g)
    #pragma unroll
    for (int u = 0; u < 8; ++u) acc[g][u] = (f32x4){0.f, 0.f, 0.f, 0.f};

  // active slot sets: kc<4 -> {0,1,2,3,4,5} (r,z,i_n); kc>=4 -> {0,1,2,3,6,7} (r,z,h_n)
  bf16x8 bcur[6], bnext[6];
  #pragma unroll
  for (int i = 0; i < 6; ++i) bcur[i] = *(const bf16x8*)(bp + i * 512);

  #pragma unroll
  for (int kc = 0; kc < 8; ++kc) {
    if (kc < 7) {
      #pragma unroll
      for (int i = 0; i < 6; ++i) {
        int us = (kc + 1 < 4) ? i : (i < 4 ? i : i + 2);
        bnext[i] = *(const bf16x8*)(bp + (kc + 1) * 16384 + us * 512);
      }
    }
    bf16x8 a0 = *(const bf16x8*)&Asw[kc * 512 + lane * 8];
    bf16x8 a1 = *(const bf16x8*)&Asw[(8 + kc) * 512 + lane * 8];
    #pragma unroll
    for (int i = 0; i < 6; ++i) {
      int u = (kc < 4) ? i : (i < 4 ? i : i + 2);
      acc[0][u] = __builtin_amdgcn_mfma_f32_16x16x32_bf16(a0, bcur[i], acc[0][u], 0, 0, 0);
      acc[1][u] = __builtin_amdgcn_mfma_f32_16x16x32_bf16(a1, bcur[i], acc[1][u], 0, 0, 0);
    }
    #pragma unroll
    for (int i = 0; i < 6; ++i) bcur[i] = bnext[i];
  }

  // biases: u = gate*2+hu, within-gate col cw = wave*32 + hu*16 + nl
  float bias[8];
  #pragma unroll
  for (int u = 0; u < 8; ++u) {
    int gi = u >> 1, hu = u & 1;
    int cw = wave * 32 + hu * 16 + nl;
    bias[u] = (gi == 0) ? b_ih[cw] + b_hh[cw]
            : (gi == 1) ? b_ih[128 + cw] + b_hh[128 + cw]
            : (gi == 2) ? b_ih[256 + cw]
                        : b_hh[256 + cw];
  }

  // register-resident GRU combine; direct u16 global stores
  #pragma unroll
  for (int g = 0; g < 2; ++g) {
    #pragma unroll
    for (int hu = 0; hu < 2; ++hu) {
      int cw = wave * 32 + hu * 16 + nl;     // output column
      int hbase = ((g * 8 + 4 + wave) * 4 + ((hu * 2 + (nl >> 3)) & 3)) * 128 + (nl & 7);
      #pragma unroll
      for (int i = 0; i < 4; ++i) {
        int m = quad * 4 + i;                // row within 16-row group
        float rv = sig_f(acc[g][0 + hu][i] + bias[0 + hu]);
        float zv = sig_f(acc[g][2 + hu][i] + bias[2 + hu]);
        float iv = acc[g][4 + hu][i] + bias[4 + hu];
        float hn = acc[g][6 + hu][i] + bias[6 + hu];
        float hv = bf2f(Asw[hbase + m * 8]);
        float n  = tanh_f(iv + rv * hn);
        float o  = n + zv * (hv - n);
        h_out[(size_t)(row0 + g * 16 + m) * 128 + cw] = f2bf(o);
      }
    }
  }
}

// ---------------- relu + segment mean pool (two-phase, parallel) ----------------
__global__ void k_pool_partial(const u16* __restrict__ h, const int* __restrict__ batch,
                               float* __restrict__ acc) {
  int t = threadIdx.x;  // column 0..127
  int node0 = blockIdx.x * 125;
  int node1 = node0 + 125;
  int cur = batch[node0];
  float sum = 0.f;
  for (int r = node0; r < node1; ++r) {
    int g = batch[r];
    if (g != cur) {
      atomicAdd(&acc[cur * 128 + t], sum);
      sum = 0.f;
      cur = g;
    }
    sum += fmaxf(bf2f(h[(size_t)r * 128 + t]), 0.f);
  }
  atomicAdd(&acc[cur * 128 + t], sum);
}

__global__ void k_pool_div(const float* __restrict__ acc, const int* __restrict__ batch,
                           float* __restrict__ out) {
  __shared__ int se[2];
  int g = blockIdx.x, t = threadIdx.x;
  if (t < 2) {
    int target = g + t;
    int lo = 0, hi = N_NODES;
    while (lo < hi) { int mid = (lo + hi) >> 1; if (batch[mid] < target) lo = mid + 1; else hi = mid; }
    se[t] = lo;
  }
  __syncthreads();
  int cnt = se[1] - se[0];
  out[g * 128 + t] = acc[g * 128 + t] / (float)(cnt > 0 ? cnt : 1);
}

extern "C" void kernel_launch(void* const* d_in, const int* in_sizes, int n_in,
                              void* d_out, int out_size, void* d_ws, size_t ws_size,
                              hipStream_t stream) {
  const float* x     = (const float*)d_in[0];
  const int*   edges = (const int*)d_in[1];
  const int*   batch = (const int*)d_in[2];
  const float* W     = (const float*)d_in[3];
  const float* w_ih  = (const float*)d_in[4];
  const float* w_hh  = (const float*)d_in[5];
  const float* b_ih  = (const float*)d_in[6];
  const float* b_hh  = (const float*)d_in[7];
  float* out = (float*)d_out;

  char* w = (char*)d_ws;
  u16* buf0    = (u16*)(w);                 // 25,600,000 B  (h / s ping)
  u16* buf1    = (u16*)(w + 25600000);      // 25,600,000 B  (h / s pong)
  u16* bsw     = (u16*)(w + 51200000);      // 1,048,576 B
  float* acc   = (float*)(w + 52300032);    // 32,768 B  (pool accumulator)
  int* offs    = (int*)(w + 52710400);      // 400,004 B
  int* gcursor = (int*)(w + 53120768);      // 1,024 B
  int* ebase   = (int*)(w + 53123328);      // 1,028 B
  int* csr     = (int*)(w + 53531136);      // 6,400,000 B  -> total ~60 MB
  u64* ebuf    = (u64*)buf1;                // 14.7 MB; buf1 dead until 1st gather

  const int* esrc = edges;
  const int* edst = edges + N_EDGES;

  hipMemsetAsync(gcursor, 0, NBUCK * sizeof(int), stream);
  k_part<<<391, 1024, 0, stream>>>(esrc, edst, gcursor, ebuf);
  k_bscan<<<1, NBUCK, 0, stream>>>(gcursor, ebase);
  k_csr<<<NBUCK, 1024, 0, stream>>>(ebuf, ebase, offs, csr);
  k_wb<<<1024, 128, 0, stream>>>(W, w_ih, w_hh, bsw);
  k_convert<<<(N_NODES * HIDDEN) / 1024, 256, 0, stream>>>(x, buf0);
  hipMemsetAsync(acc, 0, N_GRAPHS * HIDDEN * sizeof(float), stream);

  u16* hcur = buf0;
  u16* hnxt = buf1;
  for (int st = 0; st < STEPS; ++st) {
    k_gather<<<N_NODES / 4, 256, 0, stream>>>(hcur, csr, offs, hnxt);
    // in-place: each block reads only its own 32 rows of s (hnxt) and h (hcur)
    // into LDS before writing h_out (hnxt) over those same rows.
    k_gemm_gru<<<N_NODES / 32, 256, 0, stream>>>(hnxt, hcur, bsw + st * 131072,
                                                 b_ih, b_hh, hnxt);
    u16* tmp = hcur; hcur = hnxt; hnxt = tmp;
  }
  k_pool_partial<<<800, 128, 0, stream>>>(hcur, batch, acc);
  k_pool_div<<<N_GRAPHS, 128, 0, stream>>>(acc, batch, out);
}

// Round 13
// 586.445 us; speedup vs baseline: 1.3159x; 1.0198x over previous
//
#include <hip/hip_runtime.h>

#define N_NODES  100000
#define N_EDGES  1600000
#define HIDDEN   128
#define STEPS    4
#define N_GRAPHS 64
#define NBUCK    256
#define BWID     391   // nodes per bucket: 256*391 = 100096 >= 100000
#define BCAP     7168  // fixed ebuf slots per bucket (mean 6250, +11 sigma)

typedef unsigned short u16;
typedef unsigned int   u32;
typedef unsigned long long u64;
typedef __attribute__((ext_vector_type(8))) short bf16x8;
typedef __attribute__((ext_vector_type(4))) float f32x4;
typedef __attribute__((ext_vector_type(2))) float f32x2;

__device__ inline u16 f2bf(float f) {
  u32 u = __float_as_uint(f);
  u = (u + 0x7FFFu + ((u >> 16) & 1u)) >> 16;  // RTNE
  return (u16)u;
}
__device__ inline float bf2f(u16 b) { return __uint_as_float(((u32)b) << 16); }

// rcp-based activations: no IEEE division sequence, no clamps.
__device__ inline float rcp_f(float x) { return __builtin_amdgcn_rcpf(x); }
__device__ inline float sig_f(float x) { return rcp_f(1.f + __expf(-x)); }
__device__ inline float tanh_f(float x) { return 1.f - 2.f * rcp_f(1.f + __expf(2.f * x)); }

// ---------------- CSR build (bucketed multisplit, fixed-capacity buckets) ----------------
__global__ __launch_bounds__(1024) void k_part(const int* __restrict__ esrc,
                                               const int* __restrict__ edst,
                                               int* __restrict__ gcursor,
                                               u64* __restrict__ ebuf) {
  __shared__ int hist[NBUCK];
  __shared__ int base[NBUCK];
  int tid = threadIdx.x;
  if (tid < NBUCK) hist[tid] = 0;
  __syncthreads();
  int e0 = blockIdx.x * 4096;
  int sv[4], dv[4], bk[4], rk[4];
  #pragma unroll
  for (int i = 0; i < 4; ++i) {
    int e = e0 + i * 1024 + tid;
    if (e < N_EDGES) {
      sv[i] = esrc[e];
      dv[i] = edst[e];
      bk[i] = (int)((u32)dv[i] / (u32)BWID);
      rk[i] = atomicAdd(&hist[bk[i]], 1);
    } else bk[i] = -1;
  }
  __syncthreads();
  if (tid < NBUCK) base[tid] = atomicAdd(&gcursor[tid], hist[tid]);
  __syncthreads();
  #pragma unroll
  for (int i = 0; i < 4; ++i) {
    if (bk[i] >= 0) {
      int pos = bk[i] * BCAP + base[bk[i]] + rk[i];
      ebuf[pos] = ((u64)(u32)dv[i] << 32) | (u32)sv[i];
    }
  }
}

__global__ void k_bscan(const int* __restrict__ gcursor, int* __restrict__ ebase) {
  __shared__ int buf[NBUCK];
  int t = threadIdx.x;
  int v = gcursor[t];
  buf[t] = v;
  __syncthreads();
  for (int off = 1; off < NBUCK; off <<= 1) {
    int u = 0;
    if (t >= off) u = buf[t - off];
    __syncthreads();
    buf[t] += u;
    __syncthreads();
  }
  ebase[t] = buf[t] - v;
  if (t == NBUCK - 1) ebase[NBUCK] = buf[t];
}

__global__ __launch_bounds__(1024) void k_csr(const u64* __restrict__ ebuf,
                                              const int* __restrict__ ebase,
                                              int* __restrict__ offs,
                                              int* __restrict__ csr) {
  __shared__ int lcnt[512];
  __shared__ int lofs[512];
  int b = blockIdx.x, tid = threadIdx.x;
  int n0 = b * BWID;
  int n1 = min(n0 + BWID, N_NODES);
  int nn = n1 - n0;
  int e0 = ebase[b];
  int cnt = ebase[b + 1] - e0;
  const u64* ebase_p = ebuf + (size_t)b * BCAP;
  if (tid < 512) lcnt[tid] = 0;
  __syncthreads();
  for (int e = tid; e < cnt; e += 1024) {
    int dst = (int)(ebase_p[e] >> 32);
    atomicAdd(&lcnt[dst - n0], 1);
  }
  __syncthreads();
  if (tid < 512) lofs[tid] = lcnt[tid];
  __syncthreads();
  for (int off = 1; off < 512; off <<= 1) {
    int v = 0;
    if (tid < 512 && tid >= off) v = lofs[tid - off];
    __syncthreads();
    if (tid < 512 && tid >= off) lofs[tid] += v;
    __syncthreads();
  }
  int nodeoff = 0;
  if (tid < 512) nodeoff = e0 + lofs[tid] - lcnt[tid];  // exclusive
  if (tid < 512) lofs[tid] = nodeoff;                   // reuse as cursor
  if (tid < nn) offs[n0 + tid] = nodeoff;
  if (b == 0 && tid == 0) offs[N_NODES] = N_EDGES;
  __syncthreads();
  for (int e = tid; e < cnt; e += 1024) {
    u64 p = ebase_p[e];
    int src = (int)(p & 0xffffffffull);
    int dst = (int)(p >> 32);
    int pos = atomicAdd(&lofs[dst - n0], 1);
    csr[pos] = src;
  }
}

// ---------------- combined weight build ----------------
__global__ void k_wb(const float* __restrict__ W, const float* __restrict__ w_ih,
                     const float* __restrict__ w_hh, u16* __restrict__ bsw) {
  __shared__ float wrow[128];
  int b = blockIdx.x, st = b >> 8, k = b & 255, t = threadIdx.x;
  if (k < 128) wrow[t] = W[(st * 128 + k) * 128 + t];
  __syncthreads();
  int kc = k >> 5, quad = (k >> 3) & 3, kl = k & 7;
  u16* base = bsw + (size_t)st * 131072 + kc * 16384;
  #pragma unroll
  for (int gq = 0; gq < 4; ++gq) {
    int c = gq * 128 + t;
    float v;
    if (k < 128) {
      if (c < 384) {
        const float* wr = w_ih + c * 128;
        float sacc = 0.f;
        for (int j = 0; j < 128; ++j) sacc += wrow[j] * wr[j];
        v = sacc;
      } else v = 0.f;
    } else {
      int kk = k - 128;
      if (c < 256)      v = w_hh[c * 128 + kk];
      else if (c < 384) v = 0.f;
      else              v = w_hh[(c - 128) * 128 + kk];
    }
    int gi = c >> 7, cw = c & 127;
    int wv = cw >> 5, hu = (cw >> 4) & 1, nl = c & 15;
    int slot = wv * 8 + gi * 2 + hu;
    base[(slot * 4 + quad) * 128 + nl * 8 + kl] = f2bf(v);
  }
}

// ---------------- x -> bf16 ----------------
__global__ void k_convert(const float* __restrict__ x, u16* __restrict__ h) {
  int i = (blockIdx.x * 256 + threadIdx.x) * 4;
  float4 v = *(const float4*)(x + i);
  u16 o[4] = {f2bf(v.x), f2bf(v.y), f2bf(v.z), f2bf(v.w)};
  *(uint2*)(h + i) = *(uint2*)o;
}

// ---------------- neighbor gather-sum: s[dst] = sum h[src] ----------------
// One node per wave; quarter-wave q takes edges j = beg+q+4t. Main loop: 4-deep
// pipeline (16 edges). Tail: ONE masked round with all remaining (<=4/quarter)
// loads in flight (index clamped to 0, values zero-masked) -- no serialized
// 4-edge rounds. Accumulation in float2 -> v_pk_add_f32.
__device__ inline void acc8(f32x2* a, uint4 p) {
  f32x2 v;
  v.x = __uint_as_float(p.x << 16); v.y = __uint_as_float(p.x & 0xffff0000u);
  a[0] += v;
  v.x = __uint_as_float(p.y << 16); v.y = __uint_as_float(p.y & 0xffff0000u);
  a[1] += v;
  v.x = __uint_as_float(p.z << 16); v.y = __uint_as_float(p.z & 0xffff0000u);
  a[2] += v;
  v.x = __uint_as_float(p.w << 16); v.y = __uint_as_float(p.w & 0xffff0000u);
  a[3] += v;
}

__global__ void k_gather(const u16* __restrict__ h, const int* __restrict__ csr,
                         const int* __restrict__ offs, u16* __restrict__ s) {
  int node = blockIdx.x * 4 + (threadIdx.x >> 6);
  int lane = threadIdx.x & 63;
  int q   = lane >> 4;
  int sub = lane & 15;
  int beg = offs[node], end = offs[node + 1];
  f32x2 a[4];
  a[0] = a[1] = a[2] = a[3] = (f32x2){0.f, 0.f};
  int j = beg + q;
  for (; j + 12 < end; j += 16) {
    int s0 = csr[j], s1 = csr[j + 4], s2 = csr[j + 8], s3 = csr[j + 12];
    uint4 p0 = *(const uint4*)(h + (size_t)s0 * 128 + sub * 8);
    uint4 p1 = *(const uint4*)(h + (size_t)s1 * 128 + sub * 8);
    uint4 p2 = *(const uint4*)(h + (size_t)s2 * 128 + sub * 8);
    uint4 p3 = *(const uint4*)(h + (size_t)s3 * 128 + sub * 8);
    acc8(a, p0); acc8(a, p1); acc8(a, p2); acc8(a, p3);
  }
  {  // masked final round: all remaining loads issued together
    int j0 = j, j1 = j + 4, j2 = j + 8, j3 = j + 12;
    u32 m0 = (j0 < end) ? 0xffffffffu : 0u;
    u32 m1 = (j1 < end) ? 0xffffffffu : 0u;
    u32 m2 = (j2 < end) ? 0xffffffffu : 0u;
    u32 m3 = (j3 < end) ? 0xffffffffu : 0u;
    int t0 = (j0 < end) ? j0 : 0, t1 = (j1 < end) ? j1 : 0;
    int t2 = (j2 < end) ? j2 : 0, t3 = (j3 < end) ? j3 : 0;
    int s0 = csr[t0], s1 = csr[t1], s2 = csr[t2], s3 = csr[t3];
    uint4 p0 = *(const uint4*)(h + (size_t)s0 * 128 + sub * 8);
    uint4 p1 = *(const uint4*)(h + (size_t)s1 * 128 + sub * 8);
    uint4 p2 = *(const uint4*)(h + (size_t)s2 * 128 + sub * 8);
    uint4 p3 = *(const uint4*)(h + (size_t)s3 * 128 + sub * 8);
    p0.x &= m0; p0.y &= m0; p0.z &= m0; p0.w &= m0;
    p1.x &= m1; p1.y &= m1; p1.z &= m1; p1.w &= m1;
    p2.x &= m2; p2.y &= m2; p2.z &= m2; p2.w &= m2;
    p3.x &= m3; p3.y &= m3; p3.z &= m3; p3.w &= m3;
    acc8(a, p0); acc8(a, p1); acc8(a, p2); acc8(a, p3);
  }
  #pragma unroll
  for (int i = 0; i < 4; ++i) {
    a[i].x += __shfl_xor(a[i].x, 16); a[i].x += __shfl_xor(a[i].x, 32);
    a[i].y += __shfl_xor(a[i].y, 16); a[i].y += __shfl_xor(a[i].y, 32);
  }
  if (q == 0) {
    uint4 o;
    o.x = (u32)f2bf(a[0].x) | ((u32)f2bf(a[0].y) << 16);
    o.y = (u32)f2bf(a[1].x) | ((u32)f2bf(a[1].y) << 16);
    o.z = (u32)f2bf(a[2].x) | ((u32)f2bf(a[2].y) << 16);
    o.w = (u32)f2bf(a[3].x) | ((u32)f2bf(a[3].y) << 16);
    *(uint4*)(s + (size_t)node * 128 + sub * 8) = o;
  }
}

// ---------------- fused dual-GEMM + GRU cell (R12-proven) ----------------
__global__ __launch_bounds__(256, 3) void k_gemm_gru(
    const u16* __restrict__ s_mat, const u16* __restrict__ h_mat,
    const u16* __restrict__ bsw, const float* __restrict__ b_ih,
    const float* __restrict__ b_hh, u16* __restrict__ h_out) {
  __shared__ u16 Asw[8192];       // 16 KB: A=[s|h], 32 rows x 256 k, frag-ordered

  const int tid  = threadIdx.x;
  const int wave = tid >> 6;
  const int lane = tid & 63;
  const int nl   = lane & 15;
  const int quad = lane >> 4;
  const int row0 = blockIdx.x * 32;   // 3125 * 32 == 100000 exactly

  {  // stage A
    int snl = tid & 15, squad = (tid >> 4) & 3, sel = tid >> 6;
    int g = sel & 1, half = sel >> 1;
    const u16* row = (half ? h_mat : s_mat) + (size_t)(row0 + g * 16 + snl) * 128;
    #pragma unroll
    for (int kc2 = 0; kc2 < 4; ++kc2) {
      uint4 v = *(const uint4*)(row + kc2 * 32 + squad * 8);
      *(uint4*)&Asw[(((g * 8 + half * 4 + kc2) * 4 + squad) * 16 + snl) * 8] = v;
    }
  }
  __syncthreads();

  const u16* bp = bsw + wave * 8 * 512 + lane * 8;

  f32x4 acc[2][8];
  #pragma unroll
  for (int g = 0; g < 2; ++g)
    #pragma unroll
    for (int u = 0; u < 8; ++u) acc[g][u] = (f32x4){0.f, 0.f, 0.f, 0.f};

  bf16x8 bcur[6], bnext[6];
  #pragma unroll
  for (int i = 0; i < 6; ++i) bcur[i] = *(const bf16x8*)(bp + i * 512);

  #pragma unroll
  for (int kc = 0; kc < 8; ++kc) {
    if (kc < 7) {
      #pragma unroll
      for (int i = 0; i < 6; ++i) {
        int us = (kc + 1 < 4) ? i : (i < 4 ? i : i + 2);
        bnext[i] = *(const bf16x8*)(bp + (kc + 1) * 16384 + us * 512);
      }
    }
    bf16x8 a0 = *(const bf16x8*)&Asw[kc * 512 + lane * 8];
    bf16x8 a1 = *(const bf16x8*)&Asw[(8 + kc) * 512 + lane * 8];
    #pragma unroll
    for (int i = 0; i < 6; ++i) {
      int u = (kc < 4) ? i : (i < 4 ? i : i + 2);
      acc[0][u] = __builtin_amdgcn_mfma_f32_16x16x32_bf16(a0, bcur[i], acc[0][u], 0, 0, 0);
      acc[1][u] = __builtin_amdgcn_mfma_f32_16x16x32_bf16(a1, bcur[i], acc[1][u], 0, 0, 0);
    }
    #pragma unroll
    for (int i = 0; i < 6; ++i) bcur[i] = bnext[i];
  }

  float bias[8];
  #pragma unroll
  for (int u = 0; u < 8; ++u) {
    int gi = u >> 1, hu = u & 1;
    int cw = wave * 32 + hu * 16 + nl;
    bias[u] = (gi == 0) ? b_ih[cw] + b_hh[cw]
            : (gi == 1) ? b_ih[128 + cw] + b_hh[128 + cw]
            : (gi == 2) ? b_ih[256 + cw]
                        : b_hh[256 + cw];
  }

  #pragma unroll
  for (int g = 0; g < 2; ++g) {
    #pragma unroll
    for (int hu = 0; hu < 2; ++hu) {
      int cw = wave * 32 + hu * 16 + nl;
      int hbase = ((g * 8 + 4 + wave) * 4 + ((hu * 2 + (nl >> 3)) & 3)) * 128 + (nl & 7);
      #pragma unroll
      for (int i = 0; i < 4; ++i) {
        int m = quad * 4 + i;
        float rv = sig_f(acc[g][0 + hu][i] + bias[0 + hu]);
        float zv = sig_f(acc[g][2 + hu][i] + bias[2 + hu]);
        float iv = acc[g][4 + hu][i] + bias[4 + hu];
        float hn = acc[g][6 + hu][i] + bias[6 + hu];
        float hv = bf2f(Asw[hbase + m * 8]);
        float n  = tanh_f(iv + rv * hn);
        float o  = n + zv * (hv - n);
        h_out[(size_t)(row0 + g * 16 + m) * 128 + cw] = f2bf(o);
      }
    }
  }
}

// ---------------- relu + segment mean pool (two-phase, parallel) ----------------
__global__ void k_pool_partial(const u16* __restrict__ h, const int* __restrict__ batch,
                               float* __restrict__ acc) {
  int t = threadIdx.x;  // column 0..127
  int node0 = blockIdx.x * 125;
  int node1 = node0 + 125;
  int cur = batch[node0];
  float sum = 0.f;
  for (int r = node0; r < node1; ++r) {
    int g = batch[r];
    if (g != cur) {
      atomicAdd(&acc[cur * 128 + t], sum);
      sum = 0.f;
      cur = g;
    }
    sum += fmaxf(bf2f(h[(size_t)r * 128 + t]), 0.f);
  }
  atomicAdd(&acc[cur * 128 + t], sum);
}

__global__ void k_pool_div(const float* __restrict__ acc, const int* __restrict__ batch,
                           float* __restrict__ out) {
  __shared__ int se[2];
  int g = blockIdx.x, t = threadIdx.x;
  if (t < 2) {
    int target = g + t;
    int lo = 0, hi = N_NODES;
    while (lo < hi) { int mid = (lo + hi) >> 1; if (batch[mid] < target) lo = mid + 1; else hi = mid; }
    se[t] = lo;
  }
  __syncthreads();
  int cnt = se[1] - se[0];
  out[g * 128 + t] = acc[g * 128 + t] / (float)(cnt > 0 ? cnt : 1);
}

extern "C" void kernel_launch(void* const* d_in, const int* in_sizes, int n_in,
                              void* d_out, int out_size, void* d_ws, size_t ws_size,
                              hipStream_t stream) {
  const float* x     = (const float*)d_in[0];
  const int*   edges = (const int*)d_in[1];
  const int*   batch = (const int*)d_in[2];
  const float* W     = (const float*)d_in[3];
  const float* w_ih  = (const float*)d_in[4];
  const float* w_hh  = (const float*)d_in[5];
  const float* b_ih  = (const float*)d_in[6];
  const float* b_hh  = (const float*)d_in[7];
  float* out = (float*)d_out;

  char* w = (char*)d_ws;
  u16* buf0    = (u16*)(w);                 // 25,600,000 B  (h / s ping)
  u16* buf1    = (u16*)(w + 25600000);      // 25,600,000 B  (h / s pong)
  u16* bsw     = (u16*)(w + 51200000);      // 1,048,576 B
  float* acc   = (float*)(w + 52300032);    // 32,768 B  (pool accumulator)
  int* offs    = (int*)(w + 52710400);      // 400,004 B
  int* gcursor = (int*)(w + 53120768);      // 1,024 B
  int* ebase   = (int*)(w + 53123328);      // 1,028 B
  int* csr     = (int*)(w + 53531136);      // 6,400,000 B  -> total ~60 MB
  u64* ebuf    = (u64*)buf1;                // 14.7 MB; buf1 dead until 1st gather

  const int* esrc = edges;
  const int* edst = edges + N_EDGES;

  hipMemsetAsync(gcursor, 0, NBUCK * sizeof(int), stream);
  k_part<<<391, 1024, 0, stream>>>(esrc, edst, gcursor, ebuf);
  k_bscan<<<1, NBUCK, 0, stream>>>(gcursor, ebase);
  k_csr<<<NBUCK, 1024, 0, stream>>>(ebuf, ebase, offs, csr);
  k_wb<<<1024, 128, 0, stream>>>(W, w_ih, w_hh, bsw);
  k_convert<<<(N_NODES * HIDDEN) / 1024, 256, 0, stream>>>(x, buf0);
  hipMemsetAsync(acc, 0, N_GRAPHS * HIDDEN * sizeof(float), stream);

  u16* hcur = buf0;
  u16* hnxt = buf1;
  for (int st = 0; st < STEPS; ++st) {
    k_gather<<<N_NODES / 4, 256, 0, stream>>>(hcur, csr, offs, hnxt);
    // in-place: each block reads only its own 32 rows of s (hnxt) and h (hcur)
    // into LDS before writing h_out (hnxt) over those same rows.
    k_gemm_gru<<<N_NODES / 32, 256, 0, stream>>>(hnxt, hcur, bsw + st * 131072,
                                                 b_ih, b_hh, hnxt);
    u16* tmp = hcur; hcur = hnxt; hnxt = tmp;
  }
  k_pool_partial<<<800, 128, 0, stream>>>(hcur, batch, acc);
  k_pool_div<<<N_GRAPHS, 128, 0, stream>>>(acc, batch, out);
}

// Round 14
// 586.363 us; speedup vs baseline: 1.3160x; 1.0001x over previous
//
#include <hip/hip_runtime.h>

#define N_NODES  100000
#define N_EDGES  1600000
#define HIDDEN   128
#define STEPS    4
#define N_GRAPHS 64
#define NBUCK    256
#define BWID     391   // nodes per bucket: 256*391 = 100096 >= 100000
#define BCAP     7168  // fixed ebuf slots per bucket (mean 6250, +11 sigma)

typedef unsigned short u16;
typedef unsigned int   u32;
typedef unsigned long long u64;
typedef __attribute__((ext_vector_type(8))) short bf16x8;
typedef __attribute__((ext_vector_type(4))) float f32x4;
typedef __attribute__((ext_vector_type(2))) float f32x2;

__device__ inline u16 f2bf(float f) {
  u32 u = __float_as_uint(f);
  u = (u + 0x7FFFu + ((u >> 16) & 1u)) >> 16;  // RTNE
  return (u16)u;
}
__device__ inline float bf2f(u16 b) { return __uint_as_float(((u32)b) << 16); }

// rcp-based activations: no IEEE division sequence, no clamps.
__device__ inline float rcp_f(float x) { return __builtin_amdgcn_rcpf(x); }
__device__ inline float sig_f(float x) { return rcp_f(1.f + __expf(-x)); }
__device__ inline float tanh_f(float x) { return 1.f - 2.f * rcp_f(1.f + __expf(2.f * x)); }

// ---------------- CSR build (bucketed multisplit, fixed-capacity buckets) ----------------
__global__ __launch_bounds__(1024) void k_part(const int* __restrict__ esrc,
                                               const int* __restrict__ edst,
                                               int* __restrict__ gcursor,
                                               u64* __restrict__ ebuf) {
  __shared__ int hist[NBUCK];
  __shared__ int base[NBUCK];
  int tid = threadIdx.x;
  if (tid < NBUCK) hist[tid] = 0;
  __syncthreads();
  int e0 = blockIdx.x * 4096;
  int sv[4], dv[4], bk[4], rk[4];
  #pragma unroll
  for (int i = 0; i < 4; ++i) {
    int e = e0 + i * 1024 + tid;
    if (e < N_EDGES) {
      sv[i] = esrc[e];
      dv[i] = edst[e];
      bk[i] = (int)((u32)dv[i] / (u32)BWID);
      rk[i] = atomicAdd(&hist[bk[i]], 1);
    } else bk[i] = -1;
  }
  __syncthreads();
  if (tid < NBUCK) base[tid] = atomicAdd(&gcursor[tid], hist[tid]);
  __syncthreads();
  #pragma unroll
  for (int i = 0; i < 4; ++i) {
    if (bk[i] >= 0) {
      int pos = bk[i] * BCAP + base[bk[i]] + rk[i];
      ebuf[pos] = ((u64)(u32)dv[i] << 32) | (u32)sv[i];
    }
  }
}

__global__ void k_bscan(const int* __restrict__ gcursor, int* __restrict__ ebase) {
  __shared__ int buf[NBUCK];
  int t = threadIdx.x;
  int v = gcursor[t];
  buf[t] = v;
  __syncthreads();
  for (int off = 1; off < NBUCK; off <<= 1) {
    int u = 0;
    if (t >= off) u = buf[t - off];
    __syncthreads();
    buf[t] += u;
    __syncthreads();
  }
  ebase[t] = buf[t] - v;
  if (t == NBUCK - 1) ebase[NBUCK] = buf[t];
}

__global__ __launch_bounds__(1024) void k_csr(const u64* __restrict__ ebuf,
                                              const int* __restrict__ ebase,
                                              int* __restrict__ offs,
                                              int* __restrict__ csr) {
  __shared__ int lcnt[512];
  __shared__ int lofs[512];
  int b = blockIdx.x, tid = threadIdx.x;
  int n0 = b * BWID;
  int n1 = min(n0 + BWID, N_NODES);
  int nn = n1 - n0;
  int e0 = ebase[b];
  int cnt = ebase[b + 1] - e0;
  const u64* ebase_p = ebuf + (size_t)b * BCAP;
  if (tid < 512) lcnt[tid] = 0;
  __syncthreads();
  for (int e = tid; e < cnt; e += 1024) {
    int dst = (int)(ebase_p[e] >> 32);
    atomicAdd(&lcnt[dst - n0], 1);
  }
  __syncthreads();
  if (tid < 512) lofs[tid] = lcnt[tid];
  __syncthreads();
  for (int off = 1; off < 512; off <<= 1) {
    int v = 0;
    if (tid < 512 && tid >= off) v = lofs[tid - off];
    __syncthreads();
    if (tid < 512 && tid >= off) lofs[tid] += v;
    __syncthreads();
  }
  int nodeoff = 0;
  if (tid < 512) nodeoff = e0 + lofs[tid] - lcnt[tid];  // exclusive
  if (tid < 512) lofs[tid] = nodeoff;                   // reuse as cursor
  if (tid < nn) offs[n0 + tid] = nodeoff;
  if (b == 0 && tid == 0) offs[N_NODES] = N_EDGES;
  __syncthreads();
  for (int e = tid; e < cnt; e += 1024) {
    u64 p = ebase_p[e];
    int src = (int)(p & 0xffffffffull);
    int dst = (int)(p >> 32);
    int pos = atomicAdd(&lofs[dst - n0], 1);
    csr[pos] = src;
  }
}

// ---------------- combined weight build ----------------
__global__ void k_wb(const float* __restrict__ W, const float* __restrict__ w_ih,
                     const float* __restrict__ w_hh, u16* __restrict__ bsw) {
  __shared__ float wrow[128];
  int b = blockIdx.x, st = b >> 8, k = b & 255, t = threadIdx.x;
  if (k < 128) wrow[t] = W[(st * 128 + k) * 128 + t];
  __syncthreads();
  int kc = k >> 5, quad = (k >> 3) & 3, kl = k & 7;
  u16* base = bsw + (size_t)st * 131072 + kc * 16384;
  #pragma unroll
  for (int gq = 0; gq < 4; ++gq) {
    int c = gq * 128 + t;
    float v;
    if (k < 128) {
      if (c < 384) {
        const float* wr = w_ih + c * 128;
        float sacc = 0.f;
        for (int j = 0; j < 128; ++j) sacc += wrow[j] * wr[j];
        v = sacc;
      } else v = 0.f;
    } else {
      int kk = k - 128;
      if (c < 256)      v = w_hh[c * 128 + kk];
      else if (c < 384) v = 0.f;
      else              v = w_hh[(c - 128) * 128 + kk];
    }
    int gi = c >> 7, cw = c & 127;
    int wv = cw >> 5, hu = (cw >> 4) & 1, nl = c & 15;
    int slot = wv * 8 + gi * 2 + hu;
    base[(slot * 4 + quad) * 128 + nl * 8 + kl] = f2bf(v);
  }
}

// ---------------- x -> bf16 ----------------
__global__ void k_convert(const float* __restrict__ x, u16* __restrict__ h) {
  int i = (blockIdx.x * 256 + threadIdx.x) * 4;
  float4 v = *(const float4*)(x + i);
  u16 o[4] = {f2bf(v.x), f2bf(v.y), f2bf(v.z), f2bf(v.w)};
  *(uint2*)(h + i) = *(uint2*)o;
}

// ---------------- neighbor gather-sum: s[dst] = sum h[src] (R13-proven) ----------------
__device__ inline void acc8(f32x2* a, uint4 p) {
  f32x2 v;
  v.x = __uint_as_float(p.x << 16); v.y = __uint_as_float(p.x & 0xffff0000u);
  a[0] += v;
  v.x = __uint_as_float(p.y << 16); v.y = __uint_as_float(p.y & 0xffff0000u);
  a[1] += v;
  v.x = __uint_as_float(p.z << 16); v.y = __uint_as_float(p.z & 0xffff0000u);
  a[2] += v;
  v.x = __uint_as_float(p.w << 16); v.y = __uint_as_float(p.w & 0xffff0000u);
  a[3] += v;
}

__global__ void k_gather(const u16* __restrict__ h, const int* __restrict__ csr,
                         const int* __restrict__ offs, u16* __restrict__ s) {
  int node = blockIdx.x * 4 + (threadIdx.x >> 6);
  int lane = threadIdx.x & 63;
  int q   = lane >> 4;
  int sub = lane & 15;
  int beg = offs[node], end = offs[node + 1];
  f32x2 a[4];
  a[0] = a[1] = a[2] = a[3] = (f32x2){0.f, 0.f};
  int j = beg + q;
  for (; j + 12 < end; j += 16) {
    int s0 = csr[j], s1 = csr[j + 4], s2 = csr[j + 8], s3 = csr[j + 12];
    uint4 p0 = *(const uint4*)(h + (size_t)s0 * 128 + sub * 8);
    uint4 p1 = *(const uint4*)(h + (size_t)s1 * 128 + sub * 8);
    uint4 p2 = *(const uint4*)(h + (size_t)s2 * 128 + sub * 8);
    uint4 p3 = *(const uint4*)(h + (size_t)s3 * 128 + sub * 8);
    acc8(a, p0); acc8(a, p1); acc8(a, p2); acc8(a, p3);
  }
  {  // masked final round: all remaining loads issued together
    int j0 = j, j1 = j + 4, j2 = j + 8, j3 = j + 12;
    u32 m0 = (j0 < end) ? 0xffffffffu : 0u;
    u32 m1 = (j1 < end) ? 0xffffffffu : 0u;
    u32 m2 = (j2 < end) ? 0xffffffffu : 0u;
    u32 m3 = (j3 < end) ? 0xffffffffu : 0u;
    int t0 = (j0 < end) ? j0 : 0, t1 = (j1 < end) ? j1 : 0;
    int t2 = (j2 < end) ? j2 : 0, t3 = (j3 < end) ? j3 : 0;
    int s0 = csr[t0], s1 = csr[t1], s2 = csr[t2], s3 = csr[t3];
    uint4 p0 = *(const uint4*)(h + (size_t)s0 * 128 + sub * 8);
    uint4 p1 = *(const uint4*)(h + (size_t)s1 * 128 + sub * 8);
    uint4 p2 = *(const uint4*)(h + (size_t)s2 * 128 + sub * 8);
    uint4 p3 = *(const uint4*)(h + (size_t)s3 * 128 + sub * 8);
    p0.x &= m0; p0.y &= m0; p0.z &= m0; p0.w &= m0;
    p1.x &= m1; p1.y &= m1; p1.z &= m1; p1.w &= m1;
    p2.x &= m2; p2.y &= m2; p2.z &= m2; p2.w &= m2;
    p3.x &= m3; p3.y &= m3; p3.z &= m3; p3.w &= m3;
    acc8(a, p0); acc8(a, p1); acc8(a, p2); acc8(a, p3);
  }
  #pragma unroll
  for (int i = 0; i < 4; ++i) {
    a[i].x += __shfl_xor(a[i].x, 16); a[i].x += __shfl_xor(a[i].x, 32);
    a[i].y += __shfl_xor(a[i].y, 16); a[i].y += __shfl_xor(a[i].y, 32);
  }
  if (q == 0) {
    uint4 o;
    o.x = (u32)f2bf(a[0].x) | ((u32)f2bf(a[0].y) << 16);
    o.y = (u32)f2bf(a[1].x) | ((u32)f2bf(a[1].y) << 16);
    o.z = (u32)f2bf(a[2].x) | ((u32)f2bf(a[2].y) << 16);
    o.w = (u32)f2bf(a[3].x) | ((u32)f2bf(a[3].y) << 16);
    *(uint4*)(s + (size_t)node * 128 + sub * 8) = o;
  }
}

// ---------------- fused dual-GEMM + GRU cell ----------------
// 32 rows/block, 4 waves, wave w owns output cols w*32..+31 (all 4 gates).
// B direct global->VGPR, frag-ordered, with TWO-kc-ahead rotating prefetch
// (12 loads in flight covers ~300cyc L2 latency; 1-ahead only covered ~150).
// kc loop fully unrolled -> compiler renames the buffer rotation away.
// Epilogue: rcp activations + direct u16 global stores.
__global__ __launch_bounds__(256, 3) void k_gemm_gru(
    const u16* __restrict__ s_mat, const u16* __restrict__ h_mat,
    const u16* __restrict__ bsw, const float* __restrict__ b_ih,
    const float* __restrict__ b_hh, u16* __restrict__ h_out) {
  __shared__ u16 Asw[8192];       // 16 KB: A=[s|h], 32 rows x 256 k, frag-ordered

  const int tid  = threadIdx.x;
  const int wave = tid >> 6;
  const int lane = tid & 63;
  const int nl   = lane & 15;
  const int quad = lane >> 4;
  const int row0 = blockIdx.x * 32;   // 3125 * 32 == 100000 exactly

  {  // stage A
    int snl = tid & 15, squad = (tid >> 4) & 3, sel = tid >> 6;
    int g = sel & 1, half = sel >> 1;
    const u16* row = (half ? h_mat : s_mat) + (size_t)(row0 + g * 16 + snl) * 128;
    #pragma unroll
    for (int kc2 = 0; kc2 < 4; ++kc2) {
      uint4 v = *(const uint4*)(row + kc2 * 32 + squad * 8);
      *(uint4*)&Asw[(((g * 8 + half * 4 + kc2) * 4 + squad) * 16 + snl) * 8] = v;
    }
  }
  __syncthreads();

  const u16* bp = bsw + wave * 8 * 512 + lane * 8;

  f32x4 acc[2][8];
  #pragma unroll
  for (int g = 0; g < 2; ++g)
    #pragma unroll
    for (int u = 0; u < 8; ++u) acc[g][u] = (f32x4){0.f, 0.f, 0.f, 0.f};

  // active slot sets: kc<4 -> {0..3,4,5} (r,z,i_n); kc>=4 -> {0..3,6,7} (r,z,h_n)
  bf16x8 b0[6], b1[6], b2[6];
  #pragma unroll
  for (int i = 0; i < 6; ++i) b0[i] = *(const bf16x8*)(bp + i * 512);                 // kc=0
  #pragma unroll
  for (int i = 0; i < 6; ++i) b1[i] = *(const bf16x8*)(bp + 16384 + i * 512);         // kc=1

  #pragma unroll
  for (int kc = 0; kc < 8; ++kc) {
    if (kc < 6) {  // prefetch kc+2
      #pragma unroll
      for (int i = 0; i < 6; ++i) {
        int us = (kc + 2 < 4) ? i : (i < 4 ? i : i + 2);
        b2[i] = *(const bf16x8*)(bp + (kc + 2) * 16384 + us * 512);
      }
    }
    bf16x8 a0 = *(const bf16x8*)&Asw[kc * 512 + lane * 8];
    bf16x8 a1 = *(const bf16x8*)&Asw[(8 + kc) * 512 + lane * 8];
    #pragma unroll
    for (int i = 0; i < 6; ++i) {
      int u = (kc < 4) ? i : (i < 4 ? i : i + 2);
      acc[0][u] = __builtin_amdgcn_mfma_f32_16x16x32_bf16(a0, b0[i], acc[0][u], 0, 0, 0);
      acc[1][u] = __builtin_amdgcn_mfma_f32_16x16x32_bf16(a1, b0[i], acc[1][u], 0, 0, 0);
    }
    #pragma unroll
    for (int i = 0; i < 6; ++i) { b0[i] = b1[i]; b1[i] = b2[i]; }
  }

  float bias[8];
  #pragma unroll
  for (int u = 0; u < 8; ++u) {
    int gi = u >> 1, hu = u & 1;
    int cw = wave * 32 + hu * 16 + nl;
    bias[u] = (gi == 0) ? b_ih[cw] + b_hh[cw]
            : (gi == 1) ? b_ih[128 + cw] + b_hh[128 + cw]
            : (gi == 2) ? b_ih[256 + cw]
                        : b_hh[256 + cw];
  }

  #pragma unroll
  for (int g = 0; g < 2; ++g) {
    #pragma unroll
    for (int hu = 0; hu < 2; ++hu) {
      int cw = wave * 32 + hu * 16 + nl;
      int hbase = ((g * 8 + 4 + wave) * 4 + ((hu * 2 + (nl >> 3)) & 3)) * 128 + (nl & 7);
      #pragma unroll
      for (int i = 0; i < 4; ++i) {
        int m = quad * 4 + i;
        float rv = sig_f(acc[g][0 + hu][i] + bias[0 + hu]);
        float zv = sig_f(acc[g][2 + hu][i] + bias[2 + hu]);
        float iv = acc[g][4 + hu][i] + bias[4 + hu];
        float hn = acc[g][6 + hu][i] + bias[6 + hu];
        float hv = bf2f(Asw[hbase + m * 8]);
        float n  = tanh_f(iv + rv * hn);
        float o  = n + zv * (hv - n);
        h_out[(size_t)(row0 + g * 16 + m) * 128 + cw] = f2bf(o);
      }
    }
  }
}

// ---------------- relu + segment mean pool (two-phase, parallel) ----------------
__global__ void k_pool_partial(const u16* __restrict__ h, const int* __restrict__ batch,
                               float* __restrict__ acc) {
  int t = threadIdx.x;  // column 0..127
  int node0 = blockIdx.x * 125;
  int node1 = node0 + 125;
  int cur = batch[node0];
  float sum = 0.f;
  for (int r = node0; r < node1; ++r) {
    int g = batch[r];
    if (g != cur) {
      atomicAdd(&acc[cur * 128 + t], sum);
      sum = 0.f;
      cur = g;
    }
    sum += fmaxf(bf2f(h[(size_t)r * 128 + t]), 0.f);
  }
  atomicAdd(&acc[cur * 128 + t], sum);
}

__global__ void k_pool_div(const float* __restrict__ acc, const int* __restrict__ batch,
                           float* __restrict__ out) {
  __shared__ int se[2];
  int g = blockIdx.x, t = threadIdx.x;
  if (t < 2) {
    int target = g + t;
    int lo = 0, hi = N_NODES;
    while (lo < hi) { int mid = (lo + hi) >> 1; if (batch[mid] < target) lo = mid + 1; else hi = mid; }
    se[t] = lo;
  }
  __syncthreads();
  int cnt = se[1] - se[0];
  out[g * 128 + t] = acc[g * 128 + t] / (float)(cnt > 0 ? cnt : 1);
}

extern "C" void kernel_launch(void* const* d_in, const int* in_sizes, int n_in,
                              void* d_out, int out_size, void* d_ws, size_t ws_size,
                              hipStream_t stream) {
  const float* x     = (const float*)d_in[0];
  const int*   edges = (const int*)d_in[1];
  const int*   batch = (const int*)d_in[2];
  const float* W     = (const float*)d_in[3];
  const float* w_ih  = (const float*)d_in[4];
  const float* w_hh  = (const float*)d_in[5];
  const float* b_ih  = (const float*)d_in[6];
  const float* b_hh  = (const float*)d_in[7];
  float* out = (float*)d_out;

  char* w = (char*)d_ws;
  u16* buf0    = (u16*)(w);                 // 25,600,000 B  (h / s ping)
  u16* buf1    = (u16*)(w + 25600000);      // 25,600,000 B  (h / s pong)
  u16* bsw     = (u16*)(w + 51200000);      // 1,048,576 B
  float* acc   = (float*)(w + 52300032);    // 32,768 B  (pool accumulator)
  int* offs    = (int*)(w + 52710400);      // 400,004 B
  int* gcursor = (int*)(w + 53120768);      // 1,024 B
  int* ebase   = (int*)(w + 53123328);      // 1,028 B
  int* csr     = (int*)(w + 53531136);      // 6,400,000 B  -> total ~60 MB
  u64* ebuf    = (u64*)buf1;                // 14.7 MB; buf1 dead until 1st gather

  const int* esrc = edges;
  const int* edst = edges + N_EDGES;

  hipMemsetAsync(gcursor, 0, NBUCK * sizeof(int), stream);
  k_part<<<391, 1024, 0, stream>>>(esrc, edst, gcursor, ebuf);
  k_bscan<<<1, NBUCK, 0, stream>>>(gcursor, ebase);
  k_csr<<<NBUCK, 1024, 0, stream>>>(ebuf, ebase, offs, csr);
  k_wb<<<1024, 128, 0, stream>>>(W, w_ih, w_hh, bsw);
  k_convert<<<(N_NODES * HIDDEN) / 1024, 256, 0, stream>>>(x, buf0);
  hipMemsetAsync(acc, 0, N_GRAPHS * HIDDEN * sizeof(float), stream);

  u16* hcur = buf0;
  u16* hnxt = buf1;
  for (int st = 0; st < STEPS; ++st) {
    k_gather<<<N_NODES / 4, 256, 0, stream>>>(hcur, csr, offs, hnxt);
    // in-place: each block reads only its own 32 rows of s (hnxt) and h (hcur)
    // into LDS before writing h_out (hnxt) over those same rows.
    k_gemm_gru<<<N_NODES / 32, 256, 0, stream>>>(hnxt, hcur, bsw + st * 131072,
                                                 b_ih, b_hh, hnxt);
    u16* tmp = hcur; hcur = hnxt; hnxt = tmp;
  }
  k_pool_partial<<<800, 128, 0, stream>>>(hcur, batch, acc);
  k_pool_div<<<N_GRAPHS, 128, 0, stream>>>(acc, batch, out);
}